// Round 1
// baseline (953.387 us; speedup 1.0000x reference)
//
#include <hip/hip_runtime.h>
#include <hip/hip_bf16.h>
#include <math.h>

#define NB 16384
#define NH 16
#define ND 256
#define NM 1024
#define BM 128
#define MB 64
#define NCH (NM / MB)   // 16

typedef float f32x4 __attribute__((ext_vector_type(4)));
typedef short bf16x8 __attribute__((ext_vector_type(8)));
typedef unsigned short u16;

__device__ __forceinline__ u16 f2bf(float f) {
  union { float f; unsigned u; } v; v.f = f;
  unsigned r = v.u + 0x7FFFu + ((v.u >> 16) & 1u);
  return (u16)(r >> 16);
}

// dst[h][c][r] = bf16(src[h][r][c]); src is [16][R][C] fp32.
__global__ __launch_bounds__(256) void transpose_cvt(const float* __restrict__ src,
                                                     u16* __restrict__ dst,
                                                     int R, int C) {
  __shared__ float tile[64][65];
  const int h = blockIdx.z;
  const int r0 = blockIdx.y * 64, c0 = blockIdx.x * 64;
  const int tr = threadIdx.x >> 6;   // 0..3
  const int tc = threadIdx.x & 63;
  const float* s = src + (size_t)h * R * C;
#pragma unroll
  for (int i = 0; i < 16; ++i) {
    int r = i * 4 + tr;
    tile[r][tc] = s[(size_t)(r0 + r) * C + (c0 + tc)];
  }
  __syncthreads();
  u16* d = dst + ((size_t)h * C + c0) * R + r0;
#pragma unroll
  for (int i = 0; i < 16; ++i) {
    int c = i * 4 + tr;
    d[(size_t)c * R + tc] = f2bf(tile[tc][c]);
  }
}

// xp[b][i] = bf16(x[b][perm[i]])
__global__ __launch_bounds__(1024) void permute_x(const float* __restrict__ x,
                                                  const int* __restrict__ perm,
                                                  u16* __restrict__ xp) {
  const int b = blockIdx.x;
  const int t = threadIdx.x;
  const float* xr = x + (size_t)b * 4096;
  int4 p = *(const int4*)(perm + t * 4);
  ushort4 o;
  o.x = f2bf(xr[p.x]); o.y = f2bf(xr[p.y]);
  o.z = f2bf(xr[p.z]); o.w = f2bf(xr[p.w]);
  *(ushort4*)(xp + (size_t)b * 4096 + t * 4) = o;
}

// out[b][j] = out[b][unperm[j]] (in place, one row per block)
__global__ __launch_bounds__(1024) void unpermute_out(float* __restrict__ out,
                                                      const int* __restrict__ unperm) {
  __shared__ float row[4096];
  const int b = blockIdx.x;
  const int t = threadIdx.x;
  float* orow = out + (size_t)b * 4096;
  *(f32x4*)(row + t * 4) = *(const f32x4*)(orow + t * 4);
  __syncthreads();
  int4 u = *(const int4*)(unperm + t * 4);
  f32x4 v;
  v.x = row[u.x]; v.y = row[u.y]; v.z = row[u.z]; v.w = row[u.w];
  *(f32x4*)(orow + t * 4) = v;
}

// 16-wave MLP, LDS-BW-optimized: each wave owns a 32-row duo-strip (2x16-row
// X fragments in regs, 64 VGPR) so every LDS weight fragment is reused by 2
// MFMAs. Wave roles: q = m-quarter (16 m) in phase A, d-quarter (64 d) in
// phase B. Per wave per chunk: 8+12 = 20 ds_read_b128 for 32 MFMAs
// (vs 34 reads in the 16-row version) -> LDS pipe ~3.6K cy/chunk vs MFMA 2.5K.
__global__ __launch_bounds__(1024, 4) void mlp_fused(
    const u16* __restrict__ xp,
    const u16* __restrict__ upT,
    const u16* __restrict__ downT,
    float* __restrict__ out) {
  __shared__ __align__(16) u16 Us[2][MB * ND];   // 2x32KB [m64][d256] 512B rows
  __shared__ __align__(16) u16 Ds[2][ND * MB];   // 2x32KB [d256][m64] 128B rows
  __shared__ __align__(16) u16 Ps[BM * MB];      // 16KB   [r128][m64] 128B rows

  const int h   = blockIdx.x;
  const int rb  = blockIdx.y;
  const int tid = threadIdx.x;
  const int w   = tid >> 6;
  const int l   = tid & 63;
  const int lg  = l >> 4;
  const int ll  = l & 15;
  const int q   = w & 3;      // phase A: m-quarter (x16); phase B: d-quarter (x64)
  const int ds  = w >> 2;     // 32-row duo-strip index
  const int row0 = rb * BM;

  const char* upH = (const char*)(upT + (size_t)h * NM * ND);
  const char* dnH = (const char*)(downT + (size_t)h * ND * NM);

  // ---- X fragments: this wave's 32 rows as 2x16-row tiles, K=256 (64 VGPR)
  bf16x8 xr[2][8];
#pragma unroll
  for (int rt = 0; rt < 2; ++rt) {
    const u16* px = xp + (size_t)(row0 + ds * 32 + rt * 16 + ll) * 4096 + h * ND;
#pragma unroll
    for (int ks = 0; ks < 8; ++ks)
      xr[rt][ks] = *(const bf16x8*)(px + ks * 32 + lg * 8);
  }

  // ---- stage Up chunk [64m][256d] = 32KB (2 dwordx4/thread)
  auto stage_us = [&](int mc, int buf) {
#pragma unroll
    for (int i = 0; i < 2; ++i) {
      int t = i * 1024 + tid;
      int m = t >> 5, g = t & 31;
      const char* src = upH + (size_t)(mc * MB + m) * 512 + ((g * 16) ^ ((m & 7) << 4));
      __builtin_amdgcn_global_load_lds(
          (const __attribute__((address_space(1))) void*)src,
          (__attribute__((address_space(3))) void*)((char*)&Us[buf][0] + (size_t)t * 16),
          16, 0, 0);
    }
  };
  // ---- stage Down chunk [256d][64m] = 32KB (2 dwordx4/thread)
  auto stage_ds = [&](int mc, int buf) {
#pragma unroll
    for (int i = 0; i < 2; ++i) {
      int t = i * 1024 + tid;
      int d = t >> 3, g = t & 7;
      const char* src = dnH + (size_t)d * 2048 + mc * 128 + ((g * 16) ^ ((d & 7) << 4));
      __builtin_amdgcn_global_load_lds(
          (const __attribute__((address_space(1))) void*)src,
          (__attribute__((address_space(3))) void*)((char*)&Ds[buf][0] + (size_t)t * 16),
          16, 0, 0);
    }
  };

  f32x4 ca[2][4];   // 2 row-tiles x 4 d-tiles x 4 regs = 32 VGPR
#pragma unroll
  for (int rt = 0; rt < 2; ++rt)
#pragma unroll
    for (int j = 0; j < 4; ++j) {
      f32x4 z = {0.f, 0.f, 0.f, 0.f};
      ca[rt][j] = z;
    }

  stage_us(0, 0);
  stage_ds(0, 0);
  __syncthreads();   // chunk-0 tiles ready

  const int m    = q * 16 + ll;          // phase-A m column (within chunk)
  const int mswz = (m & 7) << 4;

  for (int mc = 0; mc < NCH; ++mc) {
    const int cur = mc & 1;
    // Only VMEM in the loop is this stage -> stays in flight across barrier1
    // (lgkm-only), drained at barrier2 after a full chunk of cover.
    if (mc + 1 < NCH) {
      stage_us(mc + 1, cur ^ 1);
      stage_ds(mc + 1, cur ^ 1);
    }

    // ---- phase A: P[32 x 16] = X_duostrip @ Up[mc, q-quarter]
    //      8 Us reads, each reused by both row-tiles -> 16 MFMAs
    f32x4 pa[2];
#pragma unroll
    for (int rt = 0; rt < 2; ++rt) {
      f32x4 z = {0.f, 0.f, 0.f, 0.f};
      pa[rt] = z;
    }
    {
      const char* usb = (const char*)&Us[cur][0];
      __builtin_amdgcn_s_setprio(1);
#pragma unroll
      for (int ks = 0; ks < 8; ++ks) {
        bf16x8 bv = *(const bf16x8*)(usb + m * 512 + ((ks * 64 + lg * 16) ^ mswz));
        pa[0] = __builtin_amdgcn_mfma_f32_16x16x32_bf16(xr[0][ks], bv, pa[0], 0, 0, 0);
        pa[1] = __builtin_amdgcn_mfma_f32_16x16x32_bf16(xr[1][ks], bv, pa[1], 0, 0, 0);
      }
      __builtin_amdgcn_s_setprio(0);
    }

    // ---- gelu (tanh approx, exp2-based) -> Ps
    // swizzle ((rr^(rr>>3))&7): rows 8 apart land on distinct 16B slots
    // (old (rr&7) left lg0/lg2 on identical banks -> 4-way write conflict)
    {
      char* psb = (char*)Ps;
#pragma unroll
      for (int rt = 0; rt < 2; ++rt)
#pragma unroll
        for (int r4 = 0; r4 < 4; ++r4) {
          float v = pa[rt][r4];
          float p = __builtin_fmaf(0.1029433f, v * v, 2.3022082f);
          float e = __builtin_amdgcn_exp2f(v * p);
          float r = __builtin_amdgcn_rcpf(e + 1.0f);
          float g = __builtin_fmaf(-v, r, v);
          int rr = ds * 32 + rt * 16 + 4 * lg + r4;
          int off = (rr * 128 + m * 2) ^ (((rr ^ (rr >> 3)) & 7) << 4);
          *(u16*)(psb + off) = f2bf(g);
        }
    }

    // barrier1: Ps handoff (DS only); staged loads NOT drained here
    __builtin_amdgcn_sched_barrier(0);
    asm volatile("s_waitcnt lgkmcnt(0)" ::: "memory");
    __builtin_amdgcn_s_barrier();
    __builtin_amdgcn_sched_barrier(0);

    // ---- phase B: C[32 x 64d-quarter] += Ps_duostrip @ Down[mc, d-quarter]
    //      4 af reads + 8 Ds reads (each reused by both row-tiles) -> 16 MFMAs
    {
      const char* psb = (const char*)Ps;
      const char* dsb = (const char*)&Ds[cur][0];
      bf16x8 af[2][2];
#pragma unroll
      for (int rt = 0; rt < 2; ++rt) {
        int r = ds * 32 + rt * 16 + ll;
        int rswz = ((r ^ (r >> 3)) & 7) << 4;
#pragma unroll
        for (int ks = 0; ks < 2; ++ks)
          af[rt][ks] = *(const bf16x8*)(psb + r * 128 + ((ks * 64 + lg * 16) ^ rswz));
      }
      __builtin_amdgcn_s_setprio(1);
#pragma unroll
      for (int j = 0; j < 4; ++j) {
        int d = q * 64 + j * 16 + ll;
#pragma unroll
        for (int ks = 0; ks < 2; ++ks) {
          bf16x8 bv = *(const bf16x8*)(dsb + d * 128 + ((ks * 64 + lg * 16) ^ ((d & 7) << 4)));
          ca[0][j] = __builtin_amdgcn_mfma_f32_16x16x32_bf16(af[0][ks], bv, ca[0][j], 0, 0, 0);
          ca[1][j] = __builtin_amdgcn_mfma_f32_16x16x32_bf16(af[1][ks], bv, ca[1][j], 0, 0, 0);
        }
      }
      __builtin_amdgcn_s_setprio(0);
    }

    // barrier2: Ps reads done; staged tiles landed (full-chunk cover)
    __syncthreads();
  }

  // ---- epilogue: coalesced write to out[b][h*256 + d] (pre-unpermute layout)
  {
    float* ob = out + (size_t)(row0 + ds * 32) * 4096 + h * ND + q * 64;
#pragma unroll
    for (int rt = 0; rt < 2; ++rt)
#pragma unroll
      for (int r4 = 0; r4 < 4; ++r4) {
        float* orow = ob + (size_t)(rt * 16 + 4 * lg + r4) * 4096;
#pragma unroll
        for (int j = 0; j < 4; ++j)
          orow[j * 16 + ll] = ca[rt][j][r4];
      }
  }
}

extern "C" void kernel_launch(void* const* d_in, const int* in_sizes, int n_in,
                              void* d_out, int out_size, void* d_ws, size_t ws_size,
                              hipStream_t stream) {
  const float* x    = (const float*)d_in[0];
  const float* up   = (const float*)d_in[1];
  const float* down = (const float*)d_in[2];
  const int* perm   = (const int*)d_in[3];
  const int* unperm = (const int*)d_in[4];
  float* out = (float*)d_out;

  u16* upT   = (u16*)d_ws;                                   // 8 MB
  u16* downT = upT + (size_t)NH * NM * ND;                   // 8 MB
  u16* xp    = downT + (size_t)NH * NM * ND;                 // 128 MB

  // upT[h][m][d] <- up[h][d][m]   (R=256 d, C=1024 m)
  transpose_cvt<<<dim3(NM / 64, ND / 64, NH), 256, 0, stream>>>(up, upT, ND, NM);
  // downT[h][d][m] <- down[h][m][d] (R=1024 m, C=256 d)
  transpose_cvt<<<dim3(ND / 64, NM / 64, NH), 256, 0, stream>>>(down, downT, NM, ND);
  // xp[b][i] = bf16(x[b][perm[i]])
  permute_x<<<NB, 1024, 0, stream>>>(x, perm, xp);
  // main fused MLP (16 waves, 32-row duo-strips) -> out in [b][h][d] layout
  mlp_fused<<<dim3(NH, NB / BM), 1024, 0, stream>>>(xp, upT, downT, out);
  // in-place feature unpermute
  unpermute_out<<<NB, 1024, 0, stream>>>(out, unperm);
}

// Round 2
// 619.393 us; speedup vs baseline: 1.5392x; 1.5392x over previous
//
#include <hip/hip_runtime.h>
#include <hip/hip_bf16.h>
#include <math.h>

#define NB 16384
#define NH 16
#define ND 256
#define NM 1024
#define BM 128
#define MB 64
#define NCH (NM / MB)   // 16

typedef float f32x4 __attribute__((ext_vector_type(4)));
typedef short bf16x8 __attribute__((ext_vector_type(8)));
typedef unsigned short u16;

__device__ __forceinline__ u16 f2bf(float f) {
  union { float f; unsigned u; } v; v.f = f;
  unsigned r = v.u + 0x7FFFu + ((v.u >> 16) & 1u);
  return (u16)(r >> 16);
}

// dst[h][c][r] = bf16(src[h][r][c]); src is [16][R][C] fp32.
__global__ __launch_bounds__(256) void transpose_cvt(const float* __restrict__ src,
                                                     u16* __restrict__ dst,
                                                     int R, int C) {
  __shared__ float tile[64][65];
  const int h = blockIdx.z;
  const int r0 = blockIdx.y * 64, c0 = blockIdx.x * 64;
  const int tr = threadIdx.x >> 6;   // 0..3
  const int tc = threadIdx.x & 63;
  const float* s = src + (size_t)h * R * C;
#pragma unroll
  for (int i = 0; i < 16; ++i) {
    int r = i * 4 + tr;
    tile[r][tc] = s[(size_t)(r0 + r) * C + (c0 + tc)];
  }
  __syncthreads();
  u16* d = dst + ((size_t)h * C + c0) * R + r0;
#pragma unroll
  for (int i = 0; i < 16; ++i) {
    int c = i * 4 + tr;
    d[(size_t)c * R + tc] = f2bf(tile[tc][c]);
  }
}

// xp[b][i] = bf16(x[b][perm[i]])
__global__ __launch_bounds__(1024) void permute_x(const float* __restrict__ x,
                                                  const int* __restrict__ perm,
                                                  u16* __restrict__ xp) {
  const int b = blockIdx.x;
  const int t = threadIdx.x;
  const float* xr = x + (size_t)b * 4096;
  int4 p = *(const int4*)(perm + t * 4);
  ushort4 o;
  o.x = f2bf(xr[p.x]); o.y = f2bf(xr[p.y]);
  o.z = f2bf(xr[p.z]); o.w = f2bf(xr[p.w]);
  *(ushort4*)(xp + (size_t)b * 4096 + t * 4) = o;
}

// out[b][j] = out[b][unperm[j]] (in place, one row per block)
__global__ __launch_bounds__(1024) void unpermute_out(float* __restrict__ out,
                                                      const int* __restrict__ unperm) {
  __shared__ float row[4096];
  const int b = blockIdx.x;
  const int t = threadIdx.x;
  float* orow = out + (size_t)b * 4096;
  *(f32x4*)(row + t * 4) = *(const f32x4*)(orow + t * 4);
  __syncthreads();
  int4 u = *(const int4*)(unperm + t * 4);
  f32x4 v;
  v.x = row[u.x]; v.y = row[u.y]; v.z = row[u.z]; v.w = row[u.w];
  *(f32x4*)(orow + t * 4) = v;
}

// 16-wave MLP with ASYMMETRIC wave mapping (register-safe LDS-BW cut):
//  phase A: wave = (s strip of 16 rows, m-half). xr[8]=32 VGPR only -> no spill.
//  phase B: wave = (ds duo-strip of 32 rows, d-quarter). A-operand comes from
//           Ps in LDS (free rows!), each Ds fragment reused by 2 row-tiles.
// Per wave per chunk: 16 (A) + 4 af + 8 Ds = 28 ds_read_b128 for 32 MFMAs
// (vs 34 in the symmetric 16-row version; round-1's 20-read version spilled).
__global__ __launch_bounds__(1024, 4) void mlp_fused(
    const u16* __restrict__ xp,
    const u16* __restrict__ upT,
    const u16* __restrict__ downT,
    float* __restrict__ out) {
  __shared__ __align__(16) u16 Us[2][MB * ND];   // 2x32KB [m64][d256] 512B rows
  __shared__ __align__(16) u16 Ds[2][ND * MB];   // 2x32KB [d256][m64] 128B rows
  __shared__ __align__(16) u16 Ps[BM * MB];      // 16KB   [r128][m64] 128B rows

  const int h   = blockIdx.x;
  const int rb  = blockIdx.y;
  const int tid = threadIdx.x;
  const int w   = tid >> 6;
  const int l   = tid & 63;
  const int lg  = l >> 4;
  const int ll  = l & 15;
  // phase-A mapping
  const int s    = w & 7;     // 16-row strip
  const int half = w >> 3;    // m-half (x32)
  // phase-B mapping
  const int q   = w & 3;      // d-quarter (x64)
  const int ds  = w >> 2;     // 32-row duo-strip
  const int row0 = rb * BM;

  const char* upH = (const char*)(upT + (size_t)h * NM * ND);
  const char* dnH = (const char*)(downT + (size_t)h * ND * NM);

  // ---- X fragments: this wave's 16 rows (row0 + s*16 + ll), K=256 (32 VGPR)
  bf16x8 xr[8];
  {
    const u16* px = xp + (size_t)(row0 + s * 16 + ll) * 4096 + h * ND;
#pragma unroll
    for (int ks = 0; ks < 8; ++ks)
      xr[ks] = *(const bf16x8*)(px + ks * 32 + lg * 8);
  }

  // ---- stage Up chunk [64m][256d] = 32KB (2 dwordx4/thread)
  auto stage_us = [&](int mc, int buf) {
#pragma unroll
    for (int i = 0; i < 2; ++i) {
      int t = i * 1024 + tid;
      int m = t >> 5, g = t & 31;
      const char* src = upH + (size_t)(mc * MB + m) * 512 + ((g * 16) ^ ((m & 7) << 4));
      __builtin_amdgcn_global_load_lds(
          (const __attribute__((address_space(1))) void*)src,
          (__attribute__((address_space(3))) void*)((char*)&Us[buf][0] + (size_t)t * 16),
          16, 0, 0);
    }
  };
  // ---- stage Down chunk [256d][64m] = 32KB (2 dwordx4/thread)
  auto stage_ds = [&](int mc, int buf) {
#pragma unroll
    for (int i = 0; i < 2; ++i) {
      int t = i * 1024 + tid;
      int d = t >> 3, g = t & 7;
      const char* src = dnH + (size_t)d * 2048 + mc * 128 + ((g * 16) ^ ((d & 7) << 4));
      __builtin_amdgcn_global_load_lds(
          (const __attribute__((address_space(1))) void*)src,
          (__attribute__((address_space(3))) void*)((char*)&Ds[buf][0] + (size_t)t * 16),
          16, 0, 0);
    }
  };

  f32x4 ca[2][4];   // phase-B accum: 2 row-tiles x 4 d-tiles = 32 regs
#pragma unroll
  for (int rt = 0; rt < 2; ++rt)
#pragma unroll
    for (int j = 0; j < 4; ++j) {
      f32x4 z = {0.f, 0.f, 0.f, 0.f};
      ca[rt][j] = z;
    }

  stage_us(0, 0);
  stage_ds(0, 0);
  __syncthreads();   // chunk-0 tiles ready

  for (int mc = 0; mc < NCH; ++mc) {
    const int cur = mc & 1;
    // Only VMEM in the loop is this stage -> stays in flight across barrier1
    // (lgkm-only), drained at barrier2 after a full chunk of cover.
    if (mc + 1 < NCH) {
      stage_us(mc + 1, cur ^ 1);
      stage_ds(mc + 1, cur ^ 1);
    }

    // ---- phase A: P[16 x 32] = X_strip @ Up[mc, m-half]
    f32x4 pa[2];
#pragma unroll
    for (int j = 0; j < 2; ++j) {
      f32x4 z = {0.f, 0.f, 0.f, 0.f};
      pa[j] = z;
    }
    {
      const char* usb = (const char*)&Us[cur][0];
      __builtin_amdgcn_s_setprio(1);
#pragma unroll
      for (int ks = 0; ks < 8; ++ks) {
#pragma unroll
        for (int j = 0; j < 2; ++j) {
          int m = half * 32 + j * 16 + ll;
          bf16x8 bv = *(const bf16x8*)(usb + m * 512 + ((ks * 64 + lg * 16) ^ ((m & 7) << 4)));
          pa[j] = __builtin_amdgcn_mfma_f32_16x16x32_bf16(xr[ks], bv, pa[j], 0, 0, 0);
        }
      }
      __builtin_amdgcn_s_setprio(0);
    }

    // ---- gelu (tanh approx, exp2-based) -> Ps
    // swizzle ((rr^(rr>>3))&7): rows 8 apart land on distinct 16B slots
    {
      char* psb = (char*)Ps;
#pragma unroll
      for (int j = 0; j < 2; ++j)
#pragma unroll
        for (int r4 = 0; r4 < 4; ++r4) {
          float v = pa[j][r4];
          float p = __builtin_fmaf(0.1029433f, v * v, 2.3022082f);
          float e = __builtin_amdgcn_exp2f(v * p);
          float r = __builtin_amdgcn_rcpf(e + 1.0f);
          float g = __builtin_fmaf(-v, r, v);
          int rr = s * 16 + 4 * lg + r4;
          int mm = half * 32 + j * 16 + ll;
          int off = (rr * 128 + mm * 2) ^ (((rr ^ (rr >> 3)) & 7) << 4);
          *(u16*)(psb + off) = f2bf(g);
        }
    }

    // barrier1: Ps handoff (DS only); staged loads NOT drained here
    __builtin_amdgcn_sched_barrier(0);
    asm volatile("s_waitcnt lgkmcnt(0)" ::: "memory");
    __builtin_amdgcn_s_barrier();
    __builtin_amdgcn_sched_barrier(0);

    // ---- phase B: C[32 x 64d-quarter] += Ps_duostrip @ Down[mc, d-quarter]
    //      4 af reads + 8 Ds reads (each Ds reused by both row-tiles) -> 16 MFMAs
    {
      const char* psb = (const char*)Ps;
      const char* dsb = (const char*)&Ds[cur][0];
      bf16x8 af[2][2];
#pragma unroll
      for (int rt = 0; rt < 2; ++rt) {
        int r = ds * 32 + rt * 16 + ll;
        int rswz = ((r ^ (r >> 3)) & 7) << 4;
#pragma unroll
        for (int ks = 0; ks < 2; ++ks)
          af[rt][ks] = *(const bf16x8*)(psb + r * 128 + ((ks * 64 + lg * 16) ^ rswz));
      }
      __builtin_amdgcn_s_setprio(1);
#pragma unroll
      for (int j = 0; j < 4; ++j) {
        int d = q * 64 + j * 16 + ll;
#pragma unroll
        for (int ks = 0; ks < 2; ++ks) {
          bf16x8 bv = *(const bf16x8*)(dsb + d * 128 + ((ks * 64 + lg * 16) ^ ((d & 7) << 4)));
          ca[0][j] = __builtin_amdgcn_mfma_f32_16x16x32_bf16(af[0][ks], bv, ca[0][j], 0, 0, 0);
          ca[1][j] = __builtin_amdgcn_mfma_f32_16x16x32_bf16(af[1][ks], bv, ca[1][j], 0, 0, 0);
        }
      }
      __builtin_amdgcn_s_setprio(0);
    }

    // barrier2: Ps reads done; staged tiles landed (full-chunk cover)
    __syncthreads();
  }

  // ---- epilogue: coalesced write to out[b][h*256 + d] (pre-unpermute layout)
  {
    float* ob = out + (size_t)(row0 + ds * 32) * 4096 + h * ND + q * 64;
#pragma unroll
    for (int rt = 0; rt < 2; ++rt)
#pragma unroll
      for (int r4 = 0; r4 < 4; ++r4) {
        float* orow = ob + (size_t)(rt * 16 + 4 * lg + r4) * 4096;
#pragma unroll
        for (int j = 0; j < 4; ++j)
          orow[j * 16 + ll] = ca[rt][j][r4];
      }
  }
}

extern "C" void kernel_launch(void* const* d_in, const int* in_sizes, int n_in,
                              void* d_out, int out_size, void* d_ws, size_t ws_size,
                              hipStream_t stream) {
  const float* x    = (const float*)d_in[0];
  const float* up   = (const float*)d_in[1];
  const float* down = (const float*)d_in[2];
  const int* perm   = (const int*)d_in[3];
  const int* unperm = (const int*)d_in[4];
  float* out = (float*)d_out;

  u16* upT   = (u16*)d_ws;                                   // 8 MB
  u16* downT = upT + (size_t)NH * NM * ND;                   // 8 MB
  u16* xp    = downT + (size_t)NH * NM * ND;                 // 128 MB

  // upT[h][m][d] <- up[h][d][m]   (R=256 d, C=1024 m)
  transpose_cvt<<<dim3(NM / 64, ND / 64, NH), 256, 0, stream>>>(up, upT, ND, NM);
  // downT[h][d][m] <- down[h][m][d] (R=1024 m, C=256 d)
  transpose_cvt<<<dim3(ND / 64, NM / 64, NH), 256, 0, stream>>>(down, downT, NM, ND);
  // xp[b][i] = bf16(x[b][perm[i]])
  permute_x<<<NB, 1024, 0, stream>>>(x, perm, xp);
  // main fused MLP (asymmetric wave mapping) -> out in [b][h][d] layout
  mlp_fused<<<dim3(NH, NB / BM), 1024, 0, stream>>>(xp, upT, downT, out);
  // in-place feature unpermute
  unpermute_out<<<NB, 1024, 0, stream>>>(out, unperm);
}

// Round 4
// 580.493 us; speedup vs baseline: 1.6424x; 1.0670x over previous
//
#include <hip/hip_runtime.h>
#include <hip/hip_bf16.h>
#include <math.h>

#define NB 16384
#define NH 16
#define ND 256
#define NM 1024
#define BM 128
#define MB 64
#define NCH (NM / MB)   // 16

typedef float f32x4 __attribute__((ext_vector_type(4)));
typedef short bf16x8 __attribute__((ext_vector_type(8)));
typedef unsigned short u16;
typedef unsigned int u32;

__device__ __forceinline__ u16 f2bf(float f) {
  union { float f; unsigned u; } v; v.f = f;
  unsigned r = v.u + 0x7FFFu + ((v.u >> 16) & 1u);
  return (u16)(r >> 16);
}

// dst[h][c][r] = bf16(src[h][r][c]); src is [16][R][C] fp32.
__global__ __launch_bounds__(256) void transpose_cvt(const float* __restrict__ src,
                                                     u16* __restrict__ dst,
                                                     int R, int C) {
  __shared__ float tile[64][65];
  const int h = blockIdx.z;
  const int r0 = blockIdx.y * 64, c0 = blockIdx.x * 64;
  const int tr = threadIdx.x >> 6;   // 0..3
  const int tc = threadIdx.x & 63;
  const float* s = src + (size_t)h * R * C;
#pragma unroll
  for (int i = 0; i < 16; ++i) {
    int r = i * 4 + tr;
    tile[r][tc] = s[(size_t)(r0 + r) * C + (c0 + tc)];
  }
  __syncthreads();
  u16* d = dst + ((size_t)h * C + c0) * R + r0;
#pragma unroll
  for (int i = 0; i < 16; ++i) {
    int c = i * 4 + tr;
    d[(size_t)c * R + tc] = f2bf(tile[tc][c]);
  }
}

// xp[b][i] = bf16(x[b][perm[i]])
__global__ __launch_bounds__(1024) void permute_x(const float* __restrict__ x,
                                                  const int* __restrict__ perm,
                                                  u16* __restrict__ xp) {
  const int b = blockIdx.x;
  const int t = threadIdx.x;
  const float* xr = x + (size_t)b * 4096;
  int4 p = *(const int4*)(perm + t * 4);
  ushort4 o;
  o.x = f2bf(xr[p.x]); o.y = f2bf(xr[p.y]);
  o.z = f2bf(xr[p.z]); o.w = f2bf(xr[p.w]);
  *(ushort4*)(xp + (size_t)b * 4096 + t * 4) = o;
}

// out[b][j] = out[b][unperm[j]] (in place, one row per block)
__global__ __launch_bounds__(1024) void unpermute_out(float* __restrict__ out,
                                                      const int* __restrict__ unperm) {
  __shared__ float row[4096];
  const int b = blockIdx.x;
  const int t = threadIdx.x;
  float* orow = out + (size_t)b * 4096;
  *(f32x4*)(row + t * 4) = *(const f32x4*)(orow + t * 4);
  __syncthreads();
  int4 u = *(const int4*)(unperm + t * 4);
  f32x4 v;
  v.x = row[u.x]; v.y = row[u.y]; v.z = row[u.z]; v.w = row[u.w];
  *(f32x4*)(orow + t * 4) = v;
}

// 16-wave MLP, SWAPPED phase-A operands:
//  phase A computes P^T tiles via mfma(A=Up_frag, B=X_frag) -> each lane holds
//  4 CONSECUTIVE m for one x-row, so Ps is written with 2x ds_write_b64
//  (cvt_pk-packed) instead of 8x ds_write_b16. Same Us read addresses, same xr
//  registers (A/B frag layouts are symmetric: lane=row vs lane=col).
//  phase B: duo-strip mapping (4 af + 8 Ds reads, Ds reused x2).
//  Ps swizzle convention EVERYWHERE: elem at intra-row byte X of row r lives
//  at r*128 + (X ^ ((r&7)<<4)).  (Round-3 bug: write used + instead of ^.)
__global__ __launch_bounds__(1024, 4) void mlp_fused(
    const u16* __restrict__ xp,
    const u16* __restrict__ upT,
    const u16* __restrict__ downT,
    float* __restrict__ out) {
  __shared__ __align__(16) u16 Us[2][MB * ND];   // 2x32KB [m64][d256] 512B rows
  __shared__ __align__(16) u16 Ds[2][ND * MB];   // 2x32KB [d256][m64] 128B rows
  __shared__ __align__(16) u16 Ps[BM * MB];      // 16KB   [r128][m64] 128B rows

  const int h   = blockIdx.x;
  const int rb  = blockIdx.y;
  const int tid = threadIdx.x;
  const int w   = tid >> 6;
  const int l   = tid & 63;
  const int lg  = l >> 4;
  const int ll  = l & 15;
  // phase-A mapping
  const int s    = w & 7;     // 16-row strip
  const int half = w >> 3;    // m-half (x32)
  // phase-B mapping
  const int q   = w & 3;      // d-quarter (x64)
  const int ds  = w >> 2;     // 32-row duo-strip
  const int row0 = rb * BM;

  const char* upH = (const char*)(upT + (size_t)h * NM * ND);
  const char* dnH = (const char*)(downT + (size_t)h * ND * NM);

  // ---- X fragments: this wave's 16 rows (row0 + s*16 + ll), K=256 (32 VGPR)
  bf16x8 xr[8];
  {
    const u16* px = xp + (size_t)(row0 + s * 16 + ll) * 4096 + h * ND;
#pragma unroll
    for (int ks = 0; ks < 8; ++ks)
      xr[ks] = *(const bf16x8*)(px + ks * 32 + lg * 8);
  }

  // ---- stage Up chunk [64m][256d] = 32KB (2 dwordx4/thread)
  auto stage_us = [&](int mc, int buf) {
#pragma unroll
    for (int i = 0; i < 2; ++i) {
      int t = i * 1024 + tid;
      int m = t >> 5, g = t & 31;
      const char* src = upH + (size_t)(mc * MB + m) * 512 + ((g * 16) ^ ((m & 7) << 4));
      __builtin_amdgcn_global_load_lds(
          (const __attribute__((address_space(1))) void*)src,
          (__attribute__((address_space(3))) void*)((char*)&Us[buf][0] + (size_t)t * 16),
          16, 0, 0);
    }
  };
  // ---- stage Down chunk [256d][64m] = 32KB (2 dwordx4/thread)
  auto stage_ds = [&](int mc, int buf) {
#pragma unroll
    for (int i = 0; i < 2; ++i) {
      int t = i * 1024 + tid;
      int d = t >> 3, g = t & 7;
      const char* src = dnH + (size_t)d * 2048 + mc * 128 + ((g * 16) ^ ((d & 7) << 4));
      __builtin_amdgcn_global_load_lds(
          (const __attribute__((address_space(1))) void*)src,
          (__attribute__((address_space(3))) void*)((char*)&Ds[buf][0] + (size_t)t * 16),
          16, 0, 0);
    }
  };

  f32x4 ca[2][4];   // phase-B accum: 2 row-tiles x 4 d-tiles = 32 regs
#pragma unroll
  for (int rt = 0; rt < 2; ++rt)
#pragma unroll
    for (int j = 0; j < 4; ++j) {
      f32x4 z = {0.f, 0.f, 0.f, 0.f};
      ca[rt][j] = z;
    }

  stage_us(0, 0);
  stage_ds(0, 0);
  __syncthreads();   // chunk-0 tiles ready

  // Ps write base for this lane: x-row pr = s*16+ll; per-j intra-row byte
  // X = half*64 + j*32 + lg*8, stored at pr*128 + (X ^ ((pr&7)<<4)).
  const int pr = s * 16 + ll;
  const int pswz = (pr & 7) << 4;
  char* const psrow = (char*)Ps + (size_t)pr * 128;

  for (int mc = 0; mc < NCH; ++mc) {
    const int cur = mc & 1;
    // Only VMEM in the loop is this stage -> stays in flight across barrier1
    // (lgkm-only), drained at barrier2 after a full chunk of cover.
    if (mc + 1 < NCH) {
      stage_us(mc + 1, cur ^ 1);
      stage_ds(mc + 1, cur ^ 1);
    }

    // ---- phase A (swapped): Pt[32m x 16r] = Up[mc, m-half]-frags @ X_strip
    //      A-frag = Us row m (lane=row), B-frag = xr (lane=x-row as column)
    f32x4 pa[2];
#pragma unroll
    for (int j = 0; j < 2; ++j) {
      f32x4 z = {0.f, 0.f, 0.f, 0.f};
      pa[j] = z;
    }
    {
      const char* usb = (const char*)&Us[cur][0];
      __builtin_amdgcn_s_setprio(1);
#pragma unroll
      for (int ks = 0; ks < 8; ++ks) {
#pragma unroll
        for (int j = 0; j < 2; ++j) {
          int m = half * 32 + j * 16 + ll;
          bf16x8 av = *(const bf16x8*)(usb + m * 512 + ((ks * 64 + lg * 16) ^ ((m & 7) << 4)));
          pa[j] = __builtin_amdgcn_mfma_f32_16x16x32_bf16(av, xr[ks], pa[j], 0, 0, 0);
        }
      }
      __builtin_amdgcn_s_setprio(0);
    }

    // ---- gelu (tanh approx, exp2-based) -> pack pairs -> 2x ds_write_b64
    // pa[j][r4] = P[x-row pr][m = half*32 + j*16 + 4*lg + r4]
    {
#pragma unroll
      for (int j = 0; j < 2; ++j) {
        float gv[4];
#pragma unroll
        for (int r4 = 0; r4 < 4; ++r4) {
          float v = pa[j][r4];
          float p = __builtin_fmaf(0.1029433f, v * v, 2.3022082f);
          float e = __builtin_amdgcn_exp2f(v * p);
          float r = __builtin_amdgcn_rcpf(e + 1.0f);
          gv[r4] = __builtin_fmaf(-v, r, v);
        }
        u32 w0, w1;
        asm("v_cvt_pk_bf16_f32 %0, %1, %2" : "=v"(w0) : "v"(gv[0]), "v"(gv[1]));
        asm("v_cvt_pk_bf16_f32 %0, %1, %2" : "=v"(w1) : "v"(gv[2]), "v"(gv[3]));
        uint2 pk; pk.x = w0; pk.y = w1;
        *(uint2*)(psrow + ((half * 64 + j * 32 + lg * 8) ^ pswz)) = pk;
      }
    }

    // barrier1: Ps handoff (DS only); staged loads NOT drained here
    __builtin_amdgcn_sched_barrier(0);
    asm volatile("s_waitcnt lgkmcnt(0)" ::: "memory");
    __builtin_amdgcn_s_barrier();
    __builtin_amdgcn_sched_barrier(0);

    // ---- phase B: C[32 x 64d-quarter] += Ps_duostrip @ Down[mc, d-quarter]
    //      4 af reads + 8 Ds reads (each Ds reused by both row-tiles) -> 16 MFMAs
    {
      const char* psb = (const char*)Ps;
      const char* dsb = (const char*)&Ds[cur][0];
      bf16x8 af[2][2];
#pragma unroll
      for (int rt = 0; rt < 2; ++rt) {
        int r = ds * 32 + rt * 16 + ll;
        int rswz = (r & 7) << 4;
#pragma unroll
        for (int ks = 0; ks < 2; ++ks)
          af[rt][ks] = *(const bf16x8*)(psb + r * 128 + ((ks * 64 + lg * 16) ^ rswz));
      }
      __builtin_amdgcn_s_setprio(1);
#pragma unroll
      for (int j = 0; j < 4; ++j) {
        int d = q * 64 + j * 16 + ll;
#pragma unroll
        for (int ks = 0; ks < 2; ++ks) {
          bf16x8 bv = *(const bf16x8*)(dsb + d * 128 + ((ks * 64 + lg * 16) ^ ((d & 7) << 4)));
          ca[0][j] = __builtin_amdgcn_mfma_f32_16x16x32_bf16(af[0][ks], bv, ca[0][j], 0, 0, 0);
          ca[1][j] = __builtin_amdgcn_mfma_f32_16x16x32_bf16(af[1][ks], bv, ca[1][j], 0, 0, 0);
        }
      }
      __builtin_amdgcn_s_setprio(0);
    }

    // barrier2: Ps reads done; staged tiles landed (full-chunk cover)
    __syncthreads();
  }

  // ---- epilogue: coalesced write to out[b][h*256 + d] (pre-unpermute layout)
  {
    float* ob = out + (size_t)(row0 + ds * 32) * 4096 + h * ND + q * 64;
#pragma unroll
    for (int rt = 0; rt < 2; ++rt)
#pragma unroll
      for (int r4 = 0; r4 < 4; ++r4) {
        float* orow = ob + (size_t)(rt * 16 + 4 * lg + r4) * 4096;
#pragma unroll
        for (int j = 0; j < 4; ++j)
          orow[j * 16 + ll] = ca[rt][j][r4];
      }
  }
}

extern "C" void kernel_launch(void* const* d_in, const int* in_sizes, int n_in,
                              void* d_out, int out_size, void* d_ws, size_t ws_size,
                              hipStream_t stream) {
  const float* x    = (const float*)d_in[0];
  const float* up   = (const float*)d_in[1];
  const float* down = (const float*)d_in[2];
  const int* perm   = (const int*)d_in[3];
  const int* unperm = (const int*)d_in[4];
  float* out = (float*)d_out;

  u16* upT   = (u16*)d_ws;                                   // 8 MB
  u16* downT = upT + (size_t)NH * NM * ND;                   // 8 MB
  u16* xp    = downT + (size_t)NH * NM * ND;                 // 128 MB

  // upT[h][m][d] <- up[h][d][m]   (R=256 d, C=1024 m)
  transpose_cvt<<<dim3(NM / 64, ND / 64, NH), 256, 0, stream>>>(up, upT, ND, NM);
  // downT[h][d][m] <- down[h][m][d] (R=1024 m, C=256 d)
  transpose_cvt<<<dim3(ND / 64, NM / 64, NH), 256, 0, stream>>>(down, downT, NM, ND);
  // xp[b][i] = bf16(x[b][perm[i]])
  permute_x<<<NB, 1024, 0, stream>>>(x, perm, xp);
  // main fused MLP (swapped phase A, packed b64 Ps writes) -> [b][h][d] layout
  mlp_fused<<<dim3(NH, NB / BM), 1024, 0, stream>>>(xp, upT, downT, out);
  // in-place feature unpermute
  unpermute_out<<<NB, 1024, 0, stream>>>(out, unperm);
}